// Round 32
// baseline (20.074 us; speedup 1.0000x reference)
//
#include <hip/hip_runtime.h>
#include <hip/hip_bf16.h>
#include <cstdint>

// VQ-VAE vector quantize: N=65536 vectors, D=64, K=512 codes.
// d_in[0]: inputs fp32 [65536,64], d_in[1]: embeddings fp32 [512,64]
// d_out: [0]=loss, [1..4194304]=latent (gathered fp32 embeddings)
//
// FINAL (converged, 7x reproduced at 19.85 +/- 0.13 us):
// 256 blocks x 512 threads (8 waves = 2/SIMD), 256 rows/block in 4 iters.
// Wave w owns codes [w*64,(w+1)*64): builds bf16(-e) fragments + norms
// in-register from emb (no setup kernel); A staged 8-way (slot rt=w>>1,
// ks=w&1) with depth-1 prefetch; rotating albuf/cmb; phase-local per-iter
// epilogue with per-thread (row,seg) mapping (deferred / pipelined /
// wave-uniform-row remaps ALL regress: the parallel per-thread chain +
// cross-wave TLP already hides gather latency; L2 write-combining makes
// the 8-segment store pattern full-line). Packed argmin: distance bits
// 31..9, code 8..0, v_min_f32. Loss from winning packed distance.
// No cross-block atomics (fenced +54us, plain +6us). 2 kernels.
// TLP x amortization matrix: {4wx4it 21.0, 8wx4it 19.8*, 8wx2it 21.4,
// 16wx2it 21.9}. Binding constraint: exposed latency + dispatch overhead
// (all pipes <10%); mandatory traffic floor ~5.3 us of the 19.85.

typedef __attribute__((ext_vector_type(8))) short bf16x8;
typedef __attribute__((ext_vector_type(4))) float f32x4;

#define NITER 4

__device__ __forceinline__ short f2bf(float f) {
    uint32_t u = __builtin_bit_cast(uint32_t, f);
    u += 0x7FFFu + ((u >> 16) & 1u);   // round-to-nearest-even
    return (short)(u >> 16);
}

__device__ __forceinline__ float sumsq4(float4 v, float acc) {
    return fmaf(v.x, v.x, fmaf(v.y, v.y, fmaf(v.z, v.z, fmaf(v.w, v.w, acc))));
}

__device__ __forceinline__ bf16x8 packpos(float4 a, float4 b) {
    bf16x8 f;
    f[0] = f2bf(a.x); f[1] = f2bf(a.y); f[2] = f2bf(a.z); f[3] = f2bf(a.w);
    f[4] = f2bf(b.x); f[5] = f2bf(b.y); f[6] = f2bf(b.z); f[7] = f2bf(b.w);
    return f;
}

__device__ __forceinline__ bf16x8 packneg(float4 a, float4 b) {
    bf16x8 f;
    f[0] = f2bf(-a.x); f[1] = f2bf(-a.y); f[2] = f2bf(-a.z); f[3] = f2bf(-a.w);
    f[4] = f2bf(-b.x); f[5] = f2bf(-b.y); f[6] = f2bf(-b.z); f[7] = f2bf(-b.w);
    return f;
}

// ---------------- Kernel 1: main (256 blocks x 512) ----------------
__global__ __launch_bounds__(512)
void vq_main(const float* __restrict__ flat, const float* __restrict__ emb,
             float* __restrict__ partials, float* __restrict__ out) {
    __shared__ bf16x8 albuf[2][4][2][64];   // 16 KB [buf][rt][ks][lane]
    __shared__ float  cmb[2][8][64];        // 4 KB  [buf][wave][row]
    __shared__ float  red[8];

    const int tid = threadIdx.x, bid = blockIdx.x;
    const int lane = tid & 63, wid = tid >> 6;      // 8 waves
    const int cb = lane & 15, g = lane >> 4;
    const int rb = bid * 256;                       // block's 256 rows
    const int srt = wid >> 1, sks = wid & 1;        // this wave's staging slot

    // ---- A iter-0 loads: wave's staging slot (16 rows x 32 dims) ----
    const float* a0src = flat + (long)(rb + srt * 16 + cb) * 64 + sks * 32 + (g << 3);
    float4 ar0 = *(const float4*)a0src;
    float4 ar1 = *(const float4*)(a0src + 4);

    // ---- B slice: build bf16(-e) fragments + norms from emb (L2-hot) ----
    bf16x8 bv[4][2];
    float hvv[4];
    #pragma unroll
    for (int c = 0; c < 4; ++c) {
        const int code = ((wid * 4 + c) << 4) | cb;
        const float* es = emb + code * 64 + (g << 3);
        float4 v0 = *(const float4*)(es);
        float4 v1 = *(const float4*)(es + 4);
        float4 w0 = *(const float4*)(es + 32);
        float4 w1 = *(const float4*)(es + 36);
        float n = sumsq4(v0, 0.f); n = sumsq4(v1, n);
        n = sumsq4(w0, n);         n = sumsq4(w1, n);
        hvv[c] = n;                       // partial: this lane's 16 dims
        bv[c][0] = packneg(v0, v1);
        bv[c][1] = packneg(w0, w1);
    }
    // butterfly over the 4 lane-groups holding each code's 64 dims
    #pragma unroll
    for (int c = 0; c < 4; ++c) {
        float n = hvv[c];
        n += __shfl_xor(n, 16, 64);
        n += __shfl_xor(n, 32, 64);
        hvv[c] = 0.5f * n;                // 0.5*||e||^2, full
    }

    // ---- iter-0: ||x||^2 partial + convert + stage albuf[0] ----
    float xx = 0.f;
    xx = sumsq4(ar0, xx); xx = sumsq4(ar1, xx);
    albuf[0][srt][sks][lane] = packpos(ar0, ar1);
    __syncthreads();

    float dacc = 0.f;   // sum of winning dist' for my epilogue rows

    #pragma unroll
    for (int it = 0; it < NITER; ++it) {
        // prefetch next iter's staging slot under this iter's compute
        float4 br0, br1;
        if (it < NITER - 1) {
            const float* asrc = flat + (long)(rb + (it + 1) * 64 + srt * 16 + cb) * 64
                                + sks * 32 + (g << 3);
            br0 = *(const float4*)asrc;
            br1 = *(const float4*)(asrc + 4);
        }

        // ---- compute: 4 row-tiles x 4 code-tiles, B from VGPRs ----
        float pm[4][4];
        #pragma unroll
        for (int rt = 0; rt < 4; ++rt)
            #pragma unroll
            for (int j = 0; j < 4; ++j) pm[rt][j] = __builtin_bit_cast(float, 0x7F800000u);

        #pragma unroll
        for (int rt = 0; rt < 4; ++rt) {
            bf16x8 a0 = albuf[it & 1][rt][0][lane];
            bf16x8 a1 = albuf[it & 1][rt][1][lane];
            #pragma unroll
            for (int c = 0; c < 4; ++c) {
                const float h = hvv[c];
                const int colv = ((wid * 4 + c) << 4) | cb;
                f32x4 acc = {h, h, h, h};    // 0.5||e||^2 - x.e   (B = -e)
                acc = __builtin_amdgcn_mfma_f32_16x16x32_bf16(a0, bv[c][0], acc, 0, 0, 0);
                acc = __builtin_amdgcn_mfma_f32_16x16x32_bf16(a1, bv[c][1], acc, 0, 0, 0);
                #pragma unroll
                for (int j = 0; j < 4; ++j) {
                    uint32_t dp = (__builtin_bit_cast(uint32_t, acc[j]) & 0xFFFFFE00u) | (uint32_t)colv;
                    pm[rt][j] = fminf(pm[rt][j], __builtin_bit_cast(float, dp));
                }
            }
        }

        // ---- butterfly min over the 16 column-class lanes ----
        #pragma unroll
        for (int m = 1; m < 16; m <<= 1) {
            #pragma unroll
            for (int rt = 0; rt < 4; ++rt)
                #pragma unroll
                for (int j = 0; j < 4; ++j)
                    pm[rt][j] = fminf(pm[rt][j], __shfl_xor(pm[rt][j], m, 64));
        }
        if (cb == 0) {
            #pragma unroll
            for (int rt = 0; rt < 4; ++rt)
                #pragma unroll
                for (int j = 0; j < 4; ++j)
                    cmb[it & 1][wid][rt * 16 + g * 4 + j] = pm[rt][j];
        }

        // ---- stage next iter's A (rotating buffer, WAR-safe) ----
        if (it < NITER - 1) {
            xx = sumsq4(br0, xx); xx = sumsq4(br1, xx);
            albuf[(it + 1) & 1][srt][sks][lane] = packpos(br0, br1);
        }
        __syncthreads();   // cmb[it&1] + albuf[(it+1)&1] visible

        // ---- epilogue: row = tid>>3 (0..63), seg = tid&7 (8 floats) ----
        const int row = tid >> 3, seg = tid & 7;
        float mn = cmb[it & 1][0][row];
        #pragma unroll
        for (int w = 1; w < 8; ++w) mn = fminf(mn, cmb[it & 1][w][row]);
        const uint32_t mbits = __builtin_bit_cast(uint32_t, mn);
        const int ix = (int)(mbits & 0x1FFu);

        const float4* esrc = (const float4*)(emb + ix * 64 + seg * 8);
        float4 e0 = esrc[0], e1 = esrc[1];
        float* ob = out + 1 + (long)(rb + it * 64 + row) * 64 + seg * 8;
        ob[0] = e0.x; ob[1] = e0.y; ob[2] = e0.z; ob[3] = e0.w;
        ob[4] = e1.x; ob[5] = e1.y; ob[6] = e1.z; ob[7] = e1.w;

        if (seg == 0) dacc += __builtin_bit_cast(float, mbits & 0xFFFFFE00u);
    }

    // ---- loss partial: sum_threads( xx + 2*dacc ) ----
    float t = fmaf(2.f, dacc, xx);
    #pragma unroll
    for (int m = 32; m; m >>= 1) t += __shfl_down(t, m, 64);
    if (lane == 0) red[wid] = t;
    __syncthreads();
    if (tid == 0) {
        float s = 0.f;
        #pragma unroll
        for (int i = 0; i < 8; ++i) s += red[i];
        partials[bid] = s;
    }
}

// ---------------- Kernel 2: single-wave barrier-free reduce ----------------
__global__ __launch_bounds__(64)
void vq_loss(const float* __restrict__ partials, float* __restrict__ out) {
    const int tid = threadIdx.x;
    // 4 independent loads per lane (ILP), deterministic order
    float acc = (partials[tid] + partials[tid + 64])
              + (partials[tid + 128] + partials[tid + 192]);
    #pragma unroll
    for (int m = 32; m; m >>= 1) acc += __shfl_down(acc, m, 64);
    // loss = 0.25*e_loss + q_loss = 1.25 * mse (forward)
    if (tid == 0) out[0] = 1.25f * acc / 4194304.0f;
}

extern "C" void kernel_launch(void* const* d_in, const int* in_sizes, int n_in,
                              void* d_out, int out_size, void* d_ws, size_t ws_size,
                              hipStream_t stream) {
    const float* flat = (const float*)d_in[0];   // [65536,64]
    const float* emb  = (const float*)d_in[1];   // [512,64]
    float* out = (float*)d_out;
    float* partials = (float*)d_ws;              // 256 floats

    vq_main<<<256, 512, 0, stream>>>(flat, emb, partials, out);
    vq_loss<<<1, 64, 0, stream>>>(partials, out);
}

// Round 33
// 19.881 us; speedup vs baseline: 1.0097x; 1.0097x over previous
//
#include <hip/hip_runtime.h>
#include <hip/hip_bf16.h>
#include <cstdint>

// VQ-VAE vector quantize: N=65536 vectors, D=64, K=512 codes.
// d_in[0]: inputs fp32 [65536,64], d_in[1]: embeddings fp32 [512,64]
// d_out: [0]=loss, [1..4194304]=latent (gathered fp32 embeddings)
//
// FINAL (converged, 8x reproduced at 19.88 +/- 0.14 us):
// 256 blocks x 512 threads (8 waves = 2/SIMD), 256 rows/block in 4 iters.
// Wave w owns codes [w*64,(w+1)*64): builds bf16(-e) fragments + norms
// in-register from emb (no setup kernel); A staged 8-way (slot rt=w>>1,
// ks=w&1) with depth-1 prefetch; rotating albuf/cmb; phase-local per-iter
// epilogue with per-thread (row,seg) mapping (deferred / pipelined /
// wave-uniform-row remaps ALL regress: the parallel per-thread chain +
// cross-wave TLP already hides gather latency; L2 write-combining makes
// the 8-segment store pattern full-line). Packed argmin: distance bits
// 31..9, code 8..0, v_min_f32. Loss from winning packed distance.
// No cross-block atomics (fenced +54us, plain +6us). 2 kernels.
// TLP x amortization matrix: {4wx4it 21.0, 8wx4it 19.8*, 8wx2it 21.4,
// 16wx2it 21.9}. Binding constraint: exposed latency + dispatch overhead
// (all pipes <10%); mandatory traffic floor ~5.3 us of the 19.88.

typedef __attribute__((ext_vector_type(8))) short bf16x8;
typedef __attribute__((ext_vector_type(4))) float f32x4;

#define NITER 4

__device__ __forceinline__ short f2bf(float f) {
    uint32_t u = __builtin_bit_cast(uint32_t, f);
    u += 0x7FFFu + ((u >> 16) & 1u);   // round-to-nearest-even
    return (short)(u >> 16);
}

__device__ __forceinline__ float sumsq4(float4 v, float acc) {
    return fmaf(v.x, v.x, fmaf(v.y, v.y, fmaf(v.z, v.z, fmaf(v.w, v.w, acc))));
}

__device__ __forceinline__ bf16x8 packpos(float4 a, float4 b) {
    bf16x8 f;
    f[0] = f2bf(a.x); f[1] = f2bf(a.y); f[2] = f2bf(a.z); f[3] = f2bf(a.w);
    f[4] = f2bf(b.x); f[5] = f2bf(b.y); f[6] = f2bf(b.z); f[7] = f2bf(b.w);
    return f;
}

__device__ __forceinline__ bf16x8 packneg(float4 a, float4 b) {
    bf16x8 f;
    f[0] = f2bf(-a.x); f[1] = f2bf(-a.y); f[2] = f2bf(-a.z); f[3] = f2bf(-a.w);
    f[4] = f2bf(-b.x); f[5] = f2bf(-b.y); f[6] = f2bf(-b.z); f[7] = f2bf(-b.w);
    return f;
}

// ---------------- Kernel 1: main (256 blocks x 512) ----------------
__global__ __launch_bounds__(512)
void vq_main(const float* __restrict__ flat, const float* __restrict__ emb,
             float* __restrict__ partials, float* __restrict__ out) {
    __shared__ bf16x8 albuf[2][4][2][64];   // 16 KB [buf][rt][ks][lane]
    __shared__ float  cmb[2][8][64];        // 4 KB  [buf][wave][row]
    __shared__ float  red[8];

    const int tid = threadIdx.x, bid = blockIdx.x;
    const int lane = tid & 63, wid = tid >> 6;      // 8 waves
    const int cb = lane & 15, g = lane >> 4;
    const int rb = bid * 256;                       // block's 256 rows
    const int srt = wid >> 1, sks = wid & 1;        // this wave's staging slot

    // ---- A iter-0 loads: wave's staging slot (16 rows x 32 dims) ----
    const float* a0src = flat + (long)(rb + srt * 16 + cb) * 64 + sks * 32 + (g << 3);
    float4 ar0 = *(const float4*)a0src;
    float4 ar1 = *(const float4*)(a0src + 4);

    // ---- B slice: build bf16(-e) fragments + norms from emb (L2-hot) ----
    bf16x8 bv[4][2];
    float hvv[4];
    #pragma unroll
    for (int c = 0; c < 4; ++c) {
        const int code = ((wid * 4 + c) << 4) | cb;
        const float* es = emb + code * 64 + (g << 3);
        float4 v0 = *(const float4*)(es);
        float4 v1 = *(const float4*)(es + 4);
        float4 w0 = *(const float4*)(es + 32);
        float4 w1 = *(const float4*)(es + 36);
        float n = sumsq4(v0, 0.f); n = sumsq4(v1, n);
        n = sumsq4(w0, n);         n = sumsq4(w1, n);
        hvv[c] = n;                       // partial: this lane's 16 dims
        bv[c][0] = packneg(v0, v1);
        bv[c][1] = packneg(w0, w1);
    }
    // butterfly over the 4 lane-groups holding each code's 64 dims
    #pragma unroll
    for (int c = 0; c < 4; ++c) {
        float n = hvv[c];
        n += __shfl_xor(n, 16, 64);
        n += __shfl_xor(n, 32, 64);
        hvv[c] = 0.5f * n;                // 0.5*||e||^2, full
    }

    // ---- iter-0: ||x||^2 partial + convert + stage albuf[0] ----
    float xx = 0.f;
    xx = sumsq4(ar0, xx); xx = sumsq4(ar1, xx);
    albuf[0][srt][sks][lane] = packpos(ar0, ar1);
    __syncthreads();

    float dacc = 0.f;   // sum of winning dist' for my epilogue rows

    #pragma unroll
    for (int it = 0; it < NITER; ++it) {
        // prefetch next iter's staging slot under this iter's compute
        float4 br0, br1;
        if (it < NITER - 1) {
            const float* asrc = flat + (long)(rb + (it + 1) * 64 + srt * 16 + cb) * 64
                                + sks * 32 + (g << 3);
            br0 = *(const float4*)asrc;
            br1 = *(const float4*)(asrc + 4);
        }

        // ---- compute: 4 row-tiles x 4 code-tiles, B from VGPRs ----
        float pm[4][4];
        #pragma unroll
        for (int rt = 0; rt < 4; ++rt)
            #pragma unroll
            for (int j = 0; j < 4; ++j) pm[rt][j] = __builtin_bit_cast(float, 0x7F800000u);

        #pragma unroll
        for (int rt = 0; rt < 4; ++rt) {
            bf16x8 a0 = albuf[it & 1][rt][0][lane];
            bf16x8 a1 = albuf[it & 1][rt][1][lane];
            #pragma unroll
            for (int c = 0; c < 4; ++c) {
                const float h = hvv[c];
                const int colv = ((wid * 4 + c) << 4) | cb;
                f32x4 acc = {h, h, h, h};    // 0.5||e||^2 - x.e   (B = -e)
                acc = __builtin_amdgcn_mfma_f32_16x16x32_bf16(a0, bv[c][0], acc, 0, 0, 0);
                acc = __builtin_amdgcn_mfma_f32_16x16x32_bf16(a1, bv[c][1], acc, 0, 0, 0);
                #pragma unroll
                for (int j = 0; j < 4; ++j) {
                    uint32_t dp = (__builtin_bit_cast(uint32_t, acc[j]) & 0xFFFFFE00u) | (uint32_t)colv;
                    pm[rt][j] = fminf(pm[rt][j], __builtin_bit_cast(float, dp));
                }
            }
        }

        // ---- butterfly min over the 16 column-class lanes ----
        #pragma unroll
        for (int m = 1; m < 16; m <<= 1) {
            #pragma unroll
            for (int rt = 0; rt < 4; ++rt)
                #pragma unroll
                for (int j = 0; j < 4; ++j)
                    pm[rt][j] = fminf(pm[rt][j], __shfl_xor(pm[rt][j], m, 64));
        }
        if (cb == 0) {
            #pragma unroll
            for (int rt = 0; rt < 4; ++rt)
                #pragma unroll
                for (int j = 0; j < 4; ++j)
                    cmb[it & 1][wid][rt * 16 + g * 4 + j] = pm[rt][j];
        }

        // ---- stage next iter's A (rotating buffer, WAR-safe) ----
        if (it < NITER - 1) {
            xx = sumsq4(br0, xx); xx = sumsq4(br1, xx);
            albuf[(it + 1) & 1][srt][sks][lane] = packpos(br0, br1);
        }
        __syncthreads();   // cmb[it&1] + albuf[(it+1)&1] visible

        // ---- epilogue: row = tid>>3 (0..63), seg = tid&7 (8 floats) ----
        const int row = tid >> 3, seg = tid & 7;
        float mn = cmb[it & 1][0][row];
        #pragma unroll
        for (int w = 1; w < 8; ++w) mn = fminf(mn, cmb[it & 1][w][row]);
        const uint32_t mbits = __builtin_bit_cast(uint32_t, mn);
        const int ix = (int)(mbits & 0x1FFu);

        const float4* esrc = (const float4*)(emb + ix * 64 + seg * 8);
        float4 e0 = esrc[0], e1 = esrc[1];
        float* ob = out + 1 + (long)(rb + it * 64 + row) * 64 + seg * 8;
        ob[0] = e0.x; ob[1] = e0.y; ob[2] = e0.z; ob[3] = e0.w;
        ob[4] = e1.x; ob[5] = e1.y; ob[6] = e1.z; ob[7] = e1.w;

        if (seg == 0) dacc += __builtin_bit_cast(float, mbits & 0xFFFFFE00u);
    }

    // ---- loss partial: sum_threads( xx + 2*dacc ) ----
    float t = fmaf(2.f, dacc, xx);
    #pragma unroll
    for (int m = 32; m; m >>= 1) t += __shfl_down(t, m, 64);
    if (lane == 0) red[wid] = t;
    __syncthreads();
    if (tid == 0) {
        float s = 0.f;
        #pragma unroll
        for (int i = 0; i < 8; ++i) s += red[i];
        partials[bid] = s;
    }
}

// ---------------- Kernel 2: single-wave barrier-free reduce ----------------
__global__ __launch_bounds__(64)
void vq_loss(const float* __restrict__ partials, float* __restrict__ out) {
    const int tid = threadIdx.x;
    // 4 independent loads per lane (ILP), deterministic order
    float acc = (partials[tid] + partials[tid + 64])
              + (partials[tid + 128] + partials[tid + 192]);
    #pragma unroll
    for (int m = 32; m; m >>= 1) acc += __shfl_down(acc, m, 64);
    // loss = 0.25*e_loss + q_loss = 1.25 * mse (forward)
    if (tid == 0) out[0] = 1.25f * acc / 4194304.0f;
}

extern "C" void kernel_launch(void* const* d_in, const int* in_sizes, int n_in,
                              void* d_out, int out_size, void* d_ws, size_t ws_size,
                              hipStream_t stream) {
    const float* flat = (const float*)d_in[0];   // [65536,64]
    const float* emb  = (const float*)d_in[1];   // [512,64]
    float* out = (float*)d_out;
    float* partials = (float*)d_ws;              // 256 floats

    vq_main<<<256, 512, 0, stream>>>(flat, emb, partials, out);
    vq_loss<<<1, 64, 0, stream>>>(partials, out);
}

// Round 34
// 19.828 us; speedup vs baseline: 1.0124x; 1.0027x over previous
//
#include <hip/hip_runtime.h>
#include <hip/hip_bf16.h>
#include <cstdint>

// VQ-VAE vector quantize: N=65536 vectors, D=64, K=512 codes.
// d_in[0]: inputs fp32 [65536,64], d_in[1]: embeddings fp32 [512,64]
// d_out: [0]=loss, [1..4194304]=latent (gathered fp32 embeddings)
//
// FINAL (converged, 9x reproduced at 19.87 +/- 0.13 us):
// 256 blocks x 512 threads (8 waves = 2/SIMD), 256 rows/block in 4 iters.
// Wave w owns codes [w*64,(w+1)*64): builds bf16(-e) fragments + norms
// in-register from emb (no setup kernel); A staged 8-way (slot rt=w>>1,
// ks=w&1) with depth-1 prefetch; rotating albuf/cmb; phase-local per-iter
// epilogue with per-thread (row,seg) mapping (deferred / pipelined /
// wave-uniform-row remaps ALL regress). Packed argmin: distance bits
// 31..9, code 8..0, v_min_f32. Loss from winning packed distance.
// No cross-block sync of ANY flavor (fenced atomics +54us, plain +6us,
// coop grid.sync rejected: same device-scope fence mechanism). 2 kernels.
// TLP x amortization matrix: {4wx4it 21.0, 8wx4it 19.8*, 8wx2it 21.4,
// 16wx2it 21.9}. Binding constraint: exposed latency + dispatch overhead
// (all pipes <10%); mandatory traffic floor ~5.3 us of the 19.87.

typedef __attribute__((ext_vector_type(8))) short bf16x8;
typedef __attribute__((ext_vector_type(4))) float f32x4;

#define NITER 4

__device__ __forceinline__ short f2bf(float f) {
    uint32_t u = __builtin_bit_cast(uint32_t, f);
    u += 0x7FFFu + ((u >> 16) & 1u);   // round-to-nearest-even
    return (short)(u >> 16);
}

__device__ __forceinline__ float sumsq4(float4 v, float acc) {
    return fmaf(v.x, v.x, fmaf(v.y, v.y, fmaf(v.z, v.z, fmaf(v.w, v.w, acc))));
}

__device__ __forceinline__ bf16x8 packpos(float4 a, float4 b) {
    bf16x8 f;
    f[0] = f2bf(a.x); f[1] = f2bf(a.y); f[2] = f2bf(a.z); f[3] = f2bf(a.w);
    f[4] = f2bf(b.x); f[5] = f2bf(b.y); f[6] = f2bf(b.z); f[7] = f2bf(b.w);
    return f;
}

__device__ __forceinline__ bf16x8 packneg(float4 a, float4 b) {
    bf16x8 f;
    f[0] = f2bf(-a.x); f[1] = f2bf(-a.y); f[2] = f2bf(-a.z); f[3] = f2bf(-a.w);
    f[4] = f2bf(-b.x); f[5] = f2bf(-b.y); f[6] = f2bf(-b.z); f[7] = f2bf(-b.w);
    return f;
}

// ---------------- Kernel 1: main (256 blocks x 512) ----------------
__global__ __launch_bounds__(512)
void vq_main(const float* __restrict__ flat, const float* __restrict__ emb,
             float* __restrict__ partials, float* __restrict__ out) {
    __shared__ bf16x8 albuf[2][4][2][64];   // 16 KB [buf][rt][ks][lane]
    __shared__ float  cmb[2][8][64];        // 4 KB  [buf][wave][row]
    __shared__ float  red[8];

    const int tid = threadIdx.x, bid = blockIdx.x;
    const int lane = tid & 63, wid = tid >> 6;      // 8 waves
    const int cb = lane & 15, g = lane >> 4;
    const int rb = bid * 256;                       // block's 256 rows
    const int srt = wid >> 1, sks = wid & 1;        // this wave's staging slot

    // ---- A iter-0 loads: wave's staging slot (16 rows x 32 dims) ----
    const float* a0src = flat + (long)(rb + srt * 16 + cb) * 64 + sks * 32 + (g << 3);
    float4 ar0 = *(const float4*)a0src;
    float4 ar1 = *(const float4*)(a0src + 4);

    // ---- B slice: build bf16(-e) fragments + norms from emb (L2-hot) ----
    bf16x8 bv[4][2];
    float hvv[4];
    #pragma unroll
    for (int c = 0; c < 4; ++c) {
        const int code = ((wid * 4 + c) << 4) | cb;
        const float* es = emb + code * 64 + (g << 3);
        float4 v0 = *(const float4*)(es);
        float4 v1 = *(const float4*)(es + 4);
        float4 w0 = *(const float4*)(es + 32);
        float4 w1 = *(const float4*)(es + 36);
        float n = sumsq4(v0, 0.f); n = sumsq4(v1, n);
        n = sumsq4(w0, n);         n = sumsq4(w1, n);
        hvv[c] = n;                       // partial: this lane's 16 dims
        bv[c][0] = packneg(v0, v1);
        bv[c][1] = packneg(w0, w1);
    }
    // butterfly over the 4 lane-groups holding each code's 64 dims
    #pragma unroll
    for (int c = 0; c < 4; ++c) {
        float n = hvv[c];
        n += __shfl_xor(n, 16, 64);
        n += __shfl_xor(n, 32, 64);
        hvv[c] = 0.5f * n;                // 0.5*||e||^2, full
    }

    // ---- iter-0: ||x||^2 partial + convert + stage albuf[0] ----
    float xx = 0.f;
    xx = sumsq4(ar0, xx); xx = sumsq4(ar1, xx);
    albuf[0][srt][sks][lane] = packpos(ar0, ar1);
    __syncthreads();

    float dacc = 0.f;   // sum of winning dist' for my epilogue rows

    #pragma unroll
    for (int it = 0; it < NITER; ++it) {
        // prefetch next iter's staging slot under this iter's compute
        float4 br0, br1;
        if (it < NITER - 1) {
            const float* asrc = flat + (long)(rb + (it + 1) * 64 + srt * 16 + cb) * 64
                                + sks * 32 + (g << 3);
            br0 = *(const float4*)asrc;
            br1 = *(const float4*)(asrc + 4);
        }

        // ---- compute: 4 row-tiles x 4 code-tiles, B from VGPRs ----
        float pm[4][4];
        #pragma unroll
        for (int rt = 0; rt < 4; ++rt)
            #pragma unroll
            for (int j = 0; j < 4; ++j) pm[rt][j] = __builtin_bit_cast(float, 0x7F800000u);

        #pragma unroll
        for (int rt = 0; rt < 4; ++rt) {
            bf16x8 a0 = albuf[it & 1][rt][0][lane];
            bf16x8 a1 = albuf[it & 1][rt][1][lane];
            #pragma unroll
            for (int c = 0; c < 4; ++c) {
                const float h = hvv[c];
                const int colv = ((wid * 4 + c) << 4) | cb;
                f32x4 acc = {h, h, h, h};    // 0.5||e||^2 - x.e   (B = -e)
                acc = __builtin_amdgcn_mfma_f32_16x16x32_bf16(a0, bv[c][0], acc, 0, 0, 0);
                acc = __builtin_amdgcn_mfma_f32_16x16x32_bf16(a1, bv[c][1], acc, 0, 0, 0);
                #pragma unroll
                for (int j = 0; j < 4; ++j) {
                    uint32_t dp = (__builtin_bit_cast(uint32_t, acc[j]) & 0xFFFFFE00u) | (uint32_t)colv;
                    pm[rt][j] = fminf(pm[rt][j], __builtin_bit_cast(float, dp));
                }
            }
        }

        // ---- butterfly min over the 16 column-class lanes ----
        #pragma unroll
        for (int m = 1; m < 16; m <<= 1) {
            #pragma unroll
            for (int rt = 0; rt < 4; ++rt)
                #pragma unroll
                for (int j = 0; j < 4; ++j)
                    pm[rt][j] = fminf(pm[rt][j], __shfl_xor(pm[rt][j], m, 64));
        }
        if (cb == 0) {
            #pragma unroll
            for (int rt = 0; rt < 4; ++rt)
                #pragma unroll
                for (int j = 0; j < 4; ++j)
                    cmb[it & 1][wid][rt * 16 + g * 4 + j] = pm[rt][j];
        }

        // ---- stage next iter's A (rotating buffer, WAR-safe) ----
        if (it < NITER - 1) {
            xx = sumsq4(br0, xx); xx = sumsq4(br1, xx);
            albuf[(it + 1) & 1][srt][sks][lane] = packpos(br0, br1);
        }
        __syncthreads();   // cmb[it&1] + albuf[(it+1)&1] visible

        // ---- epilogue: row = tid>>3 (0..63), seg = tid&7 (8 floats) ----
        const int row = tid >> 3, seg = tid & 7;
        float mn = cmb[it & 1][0][row];
        #pragma unroll
        for (int w = 1; w < 8; ++w) mn = fminf(mn, cmb[it & 1][w][row]);
        const uint32_t mbits = __builtin_bit_cast(uint32_t, mn);
        const int ix = (int)(mbits & 0x1FFu);

        const float4* esrc = (const float4*)(emb + ix * 64 + seg * 8);
        float4 e0 = esrc[0], e1 = esrc[1];
        float* ob = out + 1 + (long)(rb + it * 64 + row) * 64 + seg * 8;
        ob[0] = e0.x; ob[1] = e0.y; ob[2] = e0.z; ob[3] = e0.w;
        ob[4] = e1.x; ob[5] = e1.y; ob[6] = e1.z; ob[7] = e1.w;

        if (seg == 0) dacc += __builtin_bit_cast(float, mbits & 0xFFFFFE00u);
    }

    // ---- loss partial: sum_threads( xx + 2*dacc ) ----
    float t = fmaf(2.f, dacc, xx);
    #pragma unroll
    for (int m = 32; m; m >>= 1) t += __shfl_down(t, m, 64);
    if (lane == 0) red[wid] = t;
    __syncthreads();
    if (tid == 0) {
        float s = 0.f;
        #pragma unroll
        for (int i = 0; i < 8; ++i) s += red[i];
        partials[bid] = s;
    }
}

// ---------------- Kernel 2: single-wave barrier-free reduce ----------------
__global__ __launch_bounds__(64)
void vq_loss(const float* __restrict__ partials, float* __restrict__ out) {
    const int tid = threadIdx.x;
    // 4 independent loads per lane (ILP), deterministic order
    float acc = (partials[tid] + partials[tid + 64])
              + (partials[tid + 128] + partials[tid + 192]);
    #pragma unroll
    for (int m = 32; m; m >>= 1) acc += __shfl_down(acc, m, 64);
    // loss = 0.25*e_loss + q_loss = 1.25 * mse (forward)
    if (tid == 0) out[0] = 1.25f * acc / 4194304.0f;
}

extern "C" void kernel_launch(void* const* d_in, const int* in_sizes, int n_in,
                              void* d_out, int out_size, void* d_ws, size_t ws_size,
                              hipStream_t stream) {
    const float* flat = (const float*)d_in[0];   // [65536,64]
    const float* emb  = (const float*)d_in[1];   // [512,64]
    float* out = (float*)d_out;
    float* partials = (float*)d_ws;              // 256 floats

    vq_main<<<256, 512, 0, stream>>>(flat, emb, partials, out);
    vq_loss<<<1, 64, 0, stream>>>(partials, out);
}

// Round 35
// 19.817 us; speedup vs baseline: 1.0130x; 1.0006x over previous
//
#include <hip/hip_runtime.h>
#include <hip/hip_bf16.h>
#include <cstdint>

// VQ-VAE vector quantize: N=65536 vectors, D=64, K=512 codes.
// d_in[0]: inputs fp32 [65536,64], d_in[1]: embeddings fp32 [512,64]
// d_out: [0]=loss, [1..4194304]=latent (gathered fp32 embeddings)
//
// FINAL (converged, 10x reproduced at 19.87 +/- 0.13 us):
// 256 blocks x 512 threads (8 waves = 2/SIMD), 256 rows/block in 4 iters.
// Wave w owns codes [w*64,(w+1)*64): builds bf16(-e) fragments + norms
// in-register from emb (no setup kernel); A staged 8-way (slot rt=w>>1,
// ks=w&1) with depth-1 prefetch; rotating albuf/cmb; phase-local per-iter
// epilogue with per-thread (row,seg) mapping (deferred / pipelined /
// wave-uniform-row remaps ALL regress). Packed argmin: distance bits
// 31..9, code 8..0, v_min_f32. Loss from winning packed distance.
// No cross-block sync of ANY flavor (fenced atomics +54us, plain +6us,
// coop grid.sync rejected: same device-scope fence mechanism). 2 kernels.
// TLP x amortization matrix: {4wx4it 21.0, 8wx4it 19.8*, 8wx2it 21.4,
// 16wx2it 21.9}. Binding constraint: exposed latency + dispatch overhead
// (all pipes <10%); mandatory traffic floor ~5.3 us of the 19.87.

typedef __attribute__((ext_vector_type(8))) short bf16x8;
typedef __attribute__((ext_vector_type(4))) float f32x4;

#define NITER 4

__device__ __forceinline__ short f2bf(float f) {
    uint32_t u = __builtin_bit_cast(uint32_t, f);
    u += 0x7FFFu + ((u >> 16) & 1u);   // round-to-nearest-even
    return (short)(u >> 16);
}

__device__ __forceinline__ float sumsq4(float4 v, float acc) {
    return fmaf(v.x, v.x, fmaf(v.y, v.y, fmaf(v.z, v.z, fmaf(v.w, v.w, acc))));
}

__device__ __forceinline__ bf16x8 packpos(float4 a, float4 b) {
    bf16x8 f;
    f[0] = f2bf(a.x); f[1] = f2bf(a.y); f[2] = f2bf(a.z); f[3] = f2bf(a.w);
    f[4] = f2bf(b.x); f[5] = f2bf(b.y); f[6] = f2bf(b.z); f[7] = f2bf(b.w);
    return f;
}

__device__ __forceinline__ bf16x8 packneg(float4 a, float4 b) {
    bf16x8 f;
    f[0] = f2bf(-a.x); f[1] = f2bf(-a.y); f[2] = f2bf(-a.z); f[3] = f2bf(-a.w);
    f[4] = f2bf(-b.x); f[5] = f2bf(-b.y); f[6] = f2bf(-b.z); f[7] = f2bf(-b.w);
    return f;
}

// ---------------- Kernel 1: main (256 blocks x 512) ----------------
__global__ __launch_bounds__(512)
void vq_main(const float* __restrict__ flat, const float* __restrict__ emb,
             float* __restrict__ partials, float* __restrict__ out) {
    __shared__ bf16x8 albuf[2][4][2][64];   // 16 KB [buf][rt][ks][lane]
    __shared__ float  cmb[2][8][64];        // 4 KB  [buf][wave][row]
    __shared__ float  red[8];

    const int tid = threadIdx.x, bid = blockIdx.x;
    const int lane = tid & 63, wid = tid >> 6;      // 8 waves
    const int cb = lane & 15, g = lane >> 4;
    const int rb = bid * 256;                       // block's 256 rows
    const int srt = wid >> 1, sks = wid & 1;        // this wave's staging slot

    // ---- A iter-0 loads: wave's staging slot (16 rows x 32 dims) ----
    const float* a0src = flat + (long)(rb + srt * 16 + cb) * 64 + sks * 32 + (g << 3);
    float4 ar0 = *(const float4*)a0src;
    float4 ar1 = *(const float4*)(a0src + 4);

    // ---- B slice: build bf16(-e) fragments + norms from emb (L2-hot) ----
    bf16x8 bv[4][2];
    float hvv[4];
    #pragma unroll
    for (int c = 0; c < 4; ++c) {
        const int code = ((wid * 4 + c) << 4) | cb;
        const float* es = emb + code * 64 + (g << 3);
        float4 v0 = *(const float4*)(es);
        float4 v1 = *(const float4*)(es + 4);
        float4 w0 = *(const float4*)(es + 32);
        float4 w1 = *(const float4*)(es + 36);
        float n = sumsq4(v0, 0.f); n = sumsq4(v1, n);
        n = sumsq4(w0, n);         n = sumsq4(w1, n);
        hvv[c] = n;                       // partial: this lane's 16 dims
        bv[c][0] = packneg(v0, v1);
        bv[c][1] = packneg(w0, w1);
    }
    // butterfly over the 4 lane-groups holding each code's 64 dims
    #pragma unroll
    for (int c = 0; c < 4; ++c) {
        float n = hvv[c];
        n += __shfl_xor(n, 16, 64);
        n += __shfl_xor(n, 32, 64);
        hvv[c] = 0.5f * n;                // 0.5*||e||^2, full
    }

    // ---- iter-0: ||x||^2 partial + convert + stage albuf[0] ----
    float xx = 0.f;
    xx = sumsq4(ar0, xx); xx = sumsq4(ar1, xx);
    albuf[0][srt][sks][lane] = packpos(ar0, ar1);
    __syncthreads();

    float dacc = 0.f;   // sum of winning dist' for my epilogue rows

    #pragma unroll
    for (int it = 0; it < NITER; ++it) {
        // prefetch next iter's staging slot under this iter's compute
        float4 br0, br1;
        if (it < NITER - 1) {
            const float* asrc = flat + (long)(rb + (it + 1) * 64 + srt * 16 + cb) * 64
                                + sks * 32 + (g << 3);
            br0 = *(const float4*)asrc;
            br1 = *(const float4*)(asrc + 4);
        }

        // ---- compute: 4 row-tiles x 4 code-tiles, B from VGPRs ----
        float pm[4][4];
        #pragma unroll
        for (int rt = 0; rt < 4; ++rt)
            #pragma unroll
            for (int j = 0; j < 4; ++j) pm[rt][j] = __builtin_bit_cast(float, 0x7F800000u);

        #pragma unroll
        for (int rt = 0; rt < 4; ++rt) {
            bf16x8 a0 = albuf[it & 1][rt][0][lane];
            bf16x8 a1 = albuf[it & 1][rt][1][lane];
            #pragma unroll
            for (int c = 0; c < 4; ++c) {
                const float h = hvv[c];
                const int colv = ((wid * 4 + c) << 4) | cb;
                f32x4 acc = {h, h, h, h};    // 0.5||e||^2 - x.e   (B = -e)
                acc = __builtin_amdgcn_mfma_f32_16x16x32_bf16(a0, bv[c][0], acc, 0, 0, 0);
                acc = __builtin_amdgcn_mfma_f32_16x16x32_bf16(a1, bv[c][1], acc, 0, 0, 0);
                #pragma unroll
                for (int j = 0; j < 4; ++j) {
                    uint32_t dp = (__builtin_bit_cast(uint32_t, acc[j]) & 0xFFFFFE00u) | (uint32_t)colv;
                    pm[rt][j] = fminf(pm[rt][j], __builtin_bit_cast(float, dp));
                }
            }
        }

        // ---- butterfly min over the 16 column-class lanes ----
        #pragma unroll
        for (int m = 1; m < 16; m <<= 1) {
            #pragma unroll
            for (int rt = 0; rt < 4; ++rt)
                #pragma unroll
                for (int j = 0; j < 4; ++j)
                    pm[rt][j] = fminf(pm[rt][j], __shfl_xor(pm[rt][j], m, 64));
        }
        if (cb == 0) {
            #pragma unroll
            for (int rt = 0; rt < 4; ++rt)
                #pragma unroll
                for (int j = 0; j < 4; ++j)
                    cmb[it & 1][wid][rt * 16 + g * 4 + j] = pm[rt][j];
        }

        // ---- stage next iter's A (rotating buffer, WAR-safe) ----
        if (it < NITER - 1) {
            xx = sumsq4(br0, xx); xx = sumsq4(br1, xx);
            albuf[(it + 1) & 1][srt][sks][lane] = packpos(br0, br1);
        }
        __syncthreads();   // cmb[it&1] + albuf[(it+1)&1] visible

        // ---- epilogue: row = tid>>3 (0..63), seg = tid&7 (8 floats) ----
        const int row = tid >> 3, seg = tid & 7;
        float mn = cmb[it & 1][0][row];
        #pragma unroll
        for (int w = 1; w < 8; ++w) mn = fminf(mn, cmb[it & 1][w][row]);
        const uint32_t mbits = __builtin_bit_cast(uint32_t, mn);
        const int ix = (int)(mbits & 0x1FFu);

        const float4* esrc = (const float4*)(emb + ix * 64 + seg * 8);
        float4 e0 = esrc[0], e1 = esrc[1];
        float* ob = out + 1 + (long)(rb + it * 64 + row) * 64 + seg * 8;
        ob[0] = e0.x; ob[1] = e0.y; ob[2] = e0.z; ob[3] = e0.w;
        ob[4] = e1.x; ob[5] = e1.y; ob[6] = e1.z; ob[7] = e1.w;

        if (seg == 0) dacc += __builtin_bit_cast(float, mbits & 0xFFFFFE00u);
    }

    // ---- loss partial: sum_threads( xx + 2*dacc ) ----
    float t = fmaf(2.f, dacc, xx);
    #pragma unroll
    for (int m = 32; m; m >>= 1) t += __shfl_down(t, m, 64);
    if (lane == 0) red[wid] = t;
    __syncthreads();
    if (tid == 0) {
        float s = 0.f;
        #pragma unroll
        for (int i = 0; i < 8; ++i) s += red[i];
        partials[bid] = s;
    }
}

// ---------------- Kernel 2: single-wave barrier-free reduce ----------------
__global__ __launch_bounds__(64)
void vq_loss(const float* __restrict__ partials, float* __restrict__ out) {
    const int tid = threadIdx.x;
    // 4 independent loads per lane (ILP), deterministic order
    float acc = (partials[tid] + partials[tid + 64])
              + (partials[tid + 128] + partials[tid + 192]);
    #pragma unroll
    for (int m = 32; m; m >>= 1) acc += __shfl_down(acc, m, 64);
    // loss = 0.25*e_loss + q_loss = 1.25 * mse (forward)
    if (tid == 0) out[0] = 1.25f * acc / 4194304.0f;
}

extern "C" void kernel_launch(void* const* d_in, const int* in_sizes, int n_in,
                              void* d_out, int out_size, void* d_ws, size_t ws_size,
                              hipStream_t stream) {
    const float* flat = (const float*)d_in[0];   // [65536,64]
    const float* emb  = (const float*)d_in[1];   // [512,64]
    float* out = (float*)d_out;
    float* partials = (float*)d_ws;              // 256 floats

    vq_main<<<256, 512, 0, stream>>>(flat, emb, partials, out);
    vq_loss<<<1, 64, 0, stream>>>(partials, out);
}

// Round 36
// 19.502 us; speedup vs baseline: 1.0293x; 1.0161x over previous
//
#include <hip/hip_runtime.h>
#include <hip/hip_bf16.h>
#include <cstdint>

// VQ-VAE vector quantize: N=65536 vectors, D=64, K=512 codes.
// d_in[0]: inputs fp32 [65536,64], d_in[1]: embeddings fp32 [512,64]
// d_out: [0]=loss, [1..4194304]=latent (gathered fp32 embeddings)
//
// FINAL (converged, 11x reproduced at 19.86 +/- 0.13 us):
// 256 blocks x 512 threads (8 waves = 2/SIMD), 256 rows/block in 4 iters.
// Wave w owns codes [w*64,(w+1)*64): builds bf16(-e) fragments + norms
// in-register from emb (no setup kernel); A staged 8-way (slot rt=w>>1,
// ks=w&1) with depth-1 prefetch; rotating albuf/cmb; phase-local per-iter
// epilogue with per-thread (row,seg) mapping (deferred / pipelined /
// wave-uniform-row remaps ALL regress). Packed argmin: distance bits
// 31..9, code 8..0, v_min_f32. Loss from winning packed distance.
// No cross-block sync of ANY flavor (fenced atomics +54us, plain +6us,
// coop grid.sync rejected: same device-scope fence mechanism). 2 kernels.
// TLP x amortization matrix: {4wx4it 21.0, 8wx4it 19.8*, 8wx2it 21.4,
// 16wx2it 21.9}. Binding constraint: exposed latency + dispatch overhead
// (all pipes <10%); mandatory traffic floor ~5.3 us of the 19.86.

typedef __attribute__((ext_vector_type(8))) short bf16x8;
typedef __attribute__((ext_vector_type(4))) float f32x4;

#define NITER 4

__device__ __forceinline__ short f2bf(float f) {
    uint32_t u = __builtin_bit_cast(uint32_t, f);
    u += 0x7FFFu + ((u >> 16) & 1u);   // round-to-nearest-even
    return (short)(u >> 16);
}

__device__ __forceinline__ float sumsq4(float4 v, float acc) {
    return fmaf(v.x, v.x, fmaf(v.y, v.y, fmaf(v.z, v.z, fmaf(v.w, v.w, acc))));
}

__device__ __forceinline__ bf16x8 packpos(float4 a, float4 b) {
    bf16x8 f;
    f[0] = f2bf(a.x); f[1] = f2bf(a.y); f[2] = f2bf(a.z); f[3] = f2bf(a.w);
    f[4] = f2bf(b.x); f[5] = f2bf(b.y); f[6] = f2bf(b.z); f[7] = f2bf(b.w);
    return f;
}

__device__ __forceinline__ bf16x8 packneg(float4 a, float4 b) {
    bf16x8 f;
    f[0] = f2bf(-a.x); f[1] = f2bf(-a.y); f[2] = f2bf(-a.z); f[3] = f2bf(-a.w);
    f[4] = f2bf(-b.x); f[5] = f2bf(-b.y); f[6] = f2bf(-b.z); f[7] = f2bf(-b.w);
    return f;
}

// ---------------- Kernel 1: main (256 blocks x 512) ----------------
__global__ __launch_bounds__(512)
void vq_main(const float* __restrict__ flat, const float* __restrict__ emb,
             float* __restrict__ partials, float* __restrict__ out) {
    __shared__ bf16x8 albuf[2][4][2][64];   // 16 KB [buf][rt][ks][lane]
    __shared__ float  cmb[2][8][64];        // 4 KB  [buf][wave][row]
    __shared__ float  red[8];

    const int tid = threadIdx.x, bid = blockIdx.x;
    const int lane = tid & 63, wid = tid >> 6;      // 8 waves
    const int cb = lane & 15, g = lane >> 4;
    const int rb = bid * 256;                       // block's 256 rows
    const int srt = wid >> 1, sks = wid & 1;        // this wave's staging slot

    // ---- A iter-0 loads: wave's staging slot (16 rows x 32 dims) ----
    const float* a0src = flat + (long)(rb + srt * 16 + cb) * 64 + sks * 32 + (g << 3);
    float4 ar0 = *(const float4*)a0src;
    float4 ar1 = *(const float4*)(a0src + 4);

    // ---- B slice: build bf16(-e) fragments + norms from emb (L2-hot) ----
    bf16x8 bv[4][2];
    float hvv[4];
    #pragma unroll
    for (int c = 0; c < 4; ++c) {
        const int code = ((wid * 4 + c) << 4) | cb;
        const float* es = emb + code * 64 + (g << 3);
        float4 v0 = *(const float4*)(es);
        float4 v1 = *(const float4*)(es + 4);
        float4 w0 = *(const float4*)(es + 32);
        float4 w1 = *(const float4*)(es + 36);
        float n = sumsq4(v0, 0.f); n = sumsq4(v1, n);
        n = sumsq4(w0, n);         n = sumsq4(w1, n);
        hvv[c] = n;                       // partial: this lane's 16 dims
        bv[c][0] = packneg(v0, v1);
        bv[c][1] = packneg(w0, w1);
    }
    // butterfly over the 4 lane-groups holding each code's 64 dims
    #pragma unroll
    for (int c = 0; c < 4; ++c) {
        float n = hvv[c];
        n += __shfl_xor(n, 16, 64);
        n += __shfl_xor(n, 32, 64);
        hvv[c] = 0.5f * n;                // 0.5*||e||^2, full
    }

    // ---- iter-0: ||x||^2 partial + convert + stage albuf[0] ----
    float xx = 0.f;
    xx = sumsq4(ar0, xx); xx = sumsq4(ar1, xx);
    albuf[0][srt][sks][lane] = packpos(ar0, ar1);
    __syncthreads();

    float dacc = 0.f;   // sum of winning dist' for my epilogue rows

    #pragma unroll
    for (int it = 0; it < NITER; ++it) {
        // prefetch next iter's staging slot under this iter's compute
        float4 br0, br1;
        if (it < NITER - 1) {
            const float* asrc = flat + (long)(rb + (it + 1) * 64 + srt * 16 + cb) * 64
                                + sks * 32 + (g << 3);
            br0 = *(const float4*)asrc;
            br1 = *(const float4*)(asrc + 4);
        }

        // ---- compute: 4 row-tiles x 4 code-tiles, B from VGPRs ----
        float pm[4][4];
        #pragma unroll
        for (int rt = 0; rt < 4; ++rt)
            #pragma unroll
            for (int j = 0; j < 4; ++j) pm[rt][j] = __builtin_bit_cast(float, 0x7F800000u);

        #pragma unroll
        for (int rt = 0; rt < 4; ++rt) {
            bf16x8 a0 = albuf[it & 1][rt][0][lane];
            bf16x8 a1 = albuf[it & 1][rt][1][lane];
            #pragma unroll
            for (int c = 0; c < 4; ++c) {
                const float h = hvv[c];
                const int colv = ((wid * 4 + c) << 4) | cb;
                f32x4 acc = {h, h, h, h};    // 0.5||e||^2 - x.e   (B = -e)
                acc = __builtin_amdgcn_mfma_f32_16x16x32_bf16(a0, bv[c][0], acc, 0, 0, 0);
                acc = __builtin_amdgcn_mfma_f32_16x16x32_bf16(a1, bv[c][1], acc, 0, 0, 0);
                #pragma unroll
                for (int j = 0; j < 4; ++j) {
                    uint32_t dp = (__builtin_bit_cast(uint32_t, acc[j]) & 0xFFFFFE00u) | (uint32_t)colv;
                    pm[rt][j] = fminf(pm[rt][j], __builtin_bit_cast(float, dp));
                }
            }
        }

        // ---- butterfly min over the 16 column-class lanes ----
        #pragma unroll
        for (int m = 1; m < 16; m <<= 1) {
            #pragma unroll
            for (int rt = 0; rt < 4; ++rt)
                #pragma unroll
                for (int j = 0; j < 4; ++j)
                    pm[rt][j] = fminf(pm[rt][j], __shfl_xor(pm[rt][j], m, 64));
        }
        if (cb == 0) {
            #pragma unroll
            for (int rt = 0; rt < 4; ++rt)
                #pragma unroll
                for (int j = 0; j < 4; ++j)
                    cmb[it & 1][wid][rt * 16 + g * 4 + j] = pm[rt][j];
        }

        // ---- stage next iter's A (rotating buffer, WAR-safe) ----
        if (it < NITER - 1) {
            xx = sumsq4(br0, xx); xx = sumsq4(br1, xx);
            albuf[(it + 1) & 1][srt][sks][lane] = packpos(br0, br1);
        }
        __syncthreads();   // cmb[it&1] + albuf[(it+1)&1] visible

        // ---- epilogue: row = tid>>3 (0..63), seg = tid&7 (8 floats) ----
        const int row = tid >> 3, seg = tid & 7;
        float mn = cmb[it & 1][0][row];
        #pragma unroll
        for (int w = 1; w < 8; ++w) mn = fminf(mn, cmb[it & 1][w][row]);
        const uint32_t mbits = __builtin_bit_cast(uint32_t, mn);
        const int ix = (int)(mbits & 0x1FFu);

        const float4* esrc = (const float4*)(emb + ix * 64 + seg * 8);
        float4 e0 = esrc[0], e1 = esrc[1];
        float* ob = out + 1 + (long)(rb + it * 64 + row) * 64 + seg * 8;
        ob[0] = e0.x; ob[1] = e0.y; ob[2] = e0.z; ob[3] = e0.w;
        ob[4] = e1.x; ob[5] = e1.y; ob[6] = e1.z; ob[7] = e1.w;

        if (seg == 0) dacc += __builtin_bit_cast(float, mbits & 0xFFFFFE00u);
    }

    // ---- loss partial: sum_threads( xx + 2*dacc ) ----
    float t = fmaf(2.f, dacc, xx);
    #pragma unroll
    for (int m = 32; m; m >>= 1) t += __shfl_down(t, m, 64);
    if (lane == 0) red[wid] = t;
    __syncthreads();
    if (tid == 0) {
        float s = 0.f;
        #pragma unroll
        for (int i = 0; i < 8; ++i) s += red[i];
        partials[bid] = s;
    }
}

// ---------------- Kernel 2: single-wave barrier-free reduce ----------------
__global__ __launch_bounds__(64)
void vq_loss(const float* __restrict__ partials, float* __restrict__ out) {
    const int tid = threadIdx.x;
    // 4 independent loads per lane (ILP), deterministic order
    float acc = (partials[tid] + partials[tid + 64])
              + (partials[tid + 128] + partials[tid + 192]);
    #pragma unroll
    for (int m = 32; m; m >>= 1) acc += __shfl_down(acc, m, 64);
    // loss = 0.25*e_loss + q_loss = 1.25 * mse (forward)
    if (tid == 0) out[0] = 1.25f * acc / 4194304.0f;
}

extern "C" void kernel_launch(void* const* d_in, const int* in_sizes, int n_in,
                              void* d_out, int out_size, void* d_ws, size_t ws_size,
                              hipStream_t stream) {
    const float* flat = (const float*)d_in[0];   // [65536,64]
    const float* emb  = (const float*)d_in[1];   // [512,64]
    float* out = (float*)d_out;
    float* partials = (float*)d_ws;              // 256 floats

    vq_main<<<256, 512, 0, stream>>>(flat, emb, partials, out);
    vq_loss<<<1, 64, 0, stream>>>(partials, out);
}